// Round 5
// baseline (248.361 us; speedup 1.0000x reference)
//
#include <hip/hip_runtime.h>
#include <hip/hip_bf16.h>

#define NROWS 65536   // B*H*W*n
#define DIM   512
#define SCALE_ 0.125f // 64^-0.5

typedef short bf16x8 __attribute__((ext_vector_type(8)));
typedef unsigned short u16x8 __attribute__((ext_vector_type(8)));
typedef float f32x4 __attribute__((ext_vector_type(4)));

__device__ __forceinline__ unsigned short f2bf(float f) {
  union { float f; unsigned u; } v; v.f = f;
  unsigned r = v.u + 0x7FFFu + ((v.u >> 16) & 1u);  // RNE
  return (unsigned short)(r >> 16);
}

// async global->LDS, 16B per lane. LDS dest is wave-uniform base + lane*16 (HW).
#define GLL16(gptr, lptr) \
  __builtin_amdgcn_global_load_lds((const __attribute__((address_space(1))) void*)(gptr), \
                                   (__attribute__((address_space(3))) void*)(lptr), 16, 0, 0)
#define VMCNT(n) asm volatile("s_waitcnt vmcnt(" #n ")" ::: "memory")
#define LGKM0   asm volatile("s_waitcnt lgkmcnt(0)" ::: "memory")

// ---------------- prep: x f32->bf16 (blocks 0..16383) + weights transpose (16384..20479) ----
__global__ void prep_kernel(const float* __restrict__ x,
                            const float* __restrict__ wqkv,
                            const float* __restrict__ wout,
                            unsigned short* __restrict__ xb,
                            unsigned short* __restrict__ wqkvT,
                            unsigned short* __restrict__ woutT) {
  if (blockIdx.x < 16384) {
    size_t i = ((size_t)blockIdx.x * 256 + threadIdx.x) * 8;
    float4 a = *(const float4*)(x + i);
    float4 b = *(const float4*)(x + i + 4);
    u16x8 p;
    p[0] = f2bf(a.x); p[1] = f2bf(a.y); p[2] = f2bf(a.z); p[3] = f2bf(a.w);
    p[4] = f2bf(b.x); p[5] = f2bf(b.y); p[6] = f2bf(b.z); p[7] = f2bf(b.w);
    *(u16x8*)(xb + i) = p;
  } else {
    int idx = (blockIdx.x - 16384) * 256 + threadIdx.x;
    if (idx < 1536 * 512) {
      int j = idx >> 9, c = idx & 511;
      wqkvT[idx] = f2bf(wqkv[(size_t)c * 1536 + j]);
    } else {
      int k2 = idx - 1536 * 512;
      int n = k2 >> 9, c = k2 & 511;
      woutT[k2] = f2bf(wout[(size_t)c * 512 + n]);
    }
  }
}

// ---------------- K1: fused QKV GEMM + attention, 8-phase-template port ----------------
// BM=128 x BN=384 (2 heads) x BK=64. 512 thr = 8 waves (2x4), per-wave 64x96.
// LDS/buf: Ak0[128][32] 8KB | Ak1 8KB | Bk0[384][32] 24KB | Bk1 24KB = 64KB. dbuf=128KB.
// 4 phases/K-tile, counted vmcnt(4), setprio around 12-MFMA clusters.
__global__ __launch_bounds__(512, 2)
void qkv_attn_kernel(const unsigned short* __restrict__ xb,
                     const float* __restrict__ mask,
                     const unsigned short* __restrict__ wqkvT,
                     unsigned short* __restrict__ attn_out) {
  __shared__ __align__(16) unsigned char smem[131072];

  const int t = threadIdx.x;
  const int lane = t & 63, w = t >> 6;
  const int wm = w >> 2, wn = w & 3;           // 2x4 waves, each 64x96
  const int fr = lane & 15, fq = lane >> 4;
  const int l4 = lane >> 2, ls = lane & 3;
  const int sigma = (ls ^ (l4 & 3)) * 8;       // source k-slot (bf16 units) for linear GLL dest
  const unsigned rko = ((unsigned)(fq ^ (fr & 3))) << 4;  // swizzled read 16B-slot

  const int per = gridDim.x >> 3;              // 2048/8
  const int lin = (blockIdx.x & 7) * per + (blockIdx.x >> 3);
  const int mtile = lin >> 2, hp = lin & 3;    // head-pair
  const int r0 = mtile * 128;
  const int head0 = hp * 2;

  f32x4 acc[4][6];
  const f32x4 z4 = {0.f, 0.f, 0.f, 0.f};
  #pragma unroll
  for (int m = 0; m < 4; ++m)
    #pragma unroll
    for (int n = 0; n < 6; ++n) acc[m][n] = z4;

  // ---- staging (identical 8-GLL sequence per wave per K-tile) ----
  auto STAGE_A = [&](int buf, int kt2, int kh) {   // 1 GLL: A rows w*16..+15
    unsigned char* dst = smem + buf * 65536 + kh * 8192 + w * 1024;
    const unsigned short* g =
        xb + (size_t)(r0 + w * 16 + l4) * 512 + kt2 * 64 + kh * 32 + sigma;
    GLL16(g, dst);
  };
  auto STAGE_B = [&](int buf, int kt2, int kh, int i) {  // 1 GLL: B rows (w*3+i)*16..+15
    int n = (w * 3 + i) * 16 + l4;                       // 0..383
    int g = n >> 7, hh = (n >> 6) & 1, j = n & 63;
    unsigned char* dst = smem + buf * 65536 + 16384 + kh * 24576 + (w * 3 + i) * 1024;
    const unsigned short* src =
        wqkvT + (size_t)((g << 9) + (head0 + hh) * 64 + j) * 512 + kt2 * 64 + kh * 32 + sigma;
    GLL16(src, dst);
  };

  auto RD_A = [&](int buf, int kh, bf16x8* a) {
    unsigned char* base = smem + buf * 65536 + kh * 8192;
    #pragma unroll
    for (int m = 0; m < 4; ++m)
      a[m] = *(const bf16x8*)(base + (unsigned)(wm * 64 + m * 16 + fr) * 64 + rko);
  };
  auto RD_B = [&](int buf, int kh, int nh, bf16x8* b) {
    unsigned char* base = smem + buf * 65536 + 16384 + kh * 24576;
    #pragma unroll
    for (int i = 0; i < 3; ++i)
      b[i] = *(const bf16x8*)(base + (unsigned)(wn * 96 + (nh * 3 + i) * 16 + fr) * 64 + rko);
  };
  auto MFMA12 = [&](bf16x8* a, bf16x8* b, int nh) {
    #pragma unroll
    for (int m = 0; m < 4; ++m)
      #pragma unroll
      for (int i = 0; i < 3; ++i)
        acc[m][nh * 3 + i] =
            __builtin_amdgcn_mfma_f32_16x16x32_bf16(a[m], b[i], acc[m][nh * 3 + i], 0, 0, 0);
  };

  // ---- prologue: stage tile 0 (G0 = k0 chunks, G1 = k1 chunks) ----
  STAGE_A(0, 0, 0); STAGE_B(0, 0, 0, 0); STAGE_B(0, 0, 0, 1); STAGE_B(0, 0, 0, 2);
  STAGE_A(0, 0, 1); STAGE_B(0, 0, 1, 0); STAGE_B(0, 0, 1, 1); STAGE_B(0, 0, 1, 2);
  VMCNT(4);               // G0(0) landed (G1(0)'s 4 still in flight)
  __syncthreads();

  for (int kt = 0; kt < 8; ++kt) {
    const int cur = kt & 1, nxt = cur ^ 1;
    const bool stg = (kt < 7);
    bf16x8 a[4], b[3];

    // ---- ph0: kk0, n0-2 ----
    RD_A(cur, 0, a); RD_B(cur, 0, 0, b);
    if (stg) { STAGE_A(nxt, kt + 1, 0); STAGE_B(nxt, kt + 1, 0, 0); }
    __builtin_amdgcn_s_barrier();
    LGKM0; __builtin_amdgcn_sched_barrier(0);
    __builtin_amdgcn_s_setprio(1);
    MFMA12(a, b, 0);
    __builtin_amdgcn_s_setprio(0);
    __builtin_amdgcn_s_barrier();

    // ---- ph1: kk0, n3-5 ----
    RD_B(cur, 0, 1, b);
    if (stg) {
      STAGE_B(nxt, kt + 1, 0, 1); STAGE_B(nxt, kt + 1, 0, 2);
      VMCNT(4);           // publish G1(kt): 4 newer (G0(kt+1)) stay in flight
    } else {
      VMCNT(0);           // kt==7: nothing newer, drain
    }
    __builtin_amdgcn_s_barrier();
    LGKM0; __builtin_amdgcn_sched_barrier(0);
    __builtin_amdgcn_s_setprio(1);
    MFMA12(a, b, 1);
    __builtin_amdgcn_s_setprio(0);
    __builtin_amdgcn_s_barrier();

    // ---- ph2: kk1, n0-2 ----
    RD_A(cur, 1, a); RD_B(cur, 1, 0, b);
    if (stg) { STAGE_A(nxt, kt + 1, 1); STAGE_B(nxt, kt + 1, 1, 0); }
    __builtin_amdgcn_s_barrier();
    LGKM0; __builtin_amdgcn_sched_barrier(0);
    __builtin_amdgcn_s_setprio(1);
    MFMA12(a, b, 0);
    __builtin_amdgcn_s_setprio(0);
    __builtin_amdgcn_s_barrier();

    // ---- ph3: kk1, n3-5 ----
    RD_B(cur, 1, 1, b);
    if (stg) {
      STAGE_B(nxt, kt + 1, 1, 1); STAGE_B(nxt, kt + 1, 1, 2);
      VMCNT(4);           // publish G0(kt+1): 4 newer (G1(kt+1)) stay in flight
    }
    __builtin_amdgcn_s_barrier();
    LGKM0; __builtin_amdgcn_sched_barrier(0);
    __builtin_amdgcn_s_setprio(1);
    MFMA12(a, b, 1);
    __builtin_amdgcn_s_setprio(0);
    __builtin_amdgcn_s_barrier();
  }

  // ---------------- epilogue: per-head attention (round-1-proven structure) ----------------
  // head h region at h*52224: Qs[128][64]swz | Ks @+16384 | VT[64][152] @+32768
  // Pl @104448: 16 global pairs x 640 ushorts.

  // mask preload (after GEMM loop so loop vmcnt counts stayed exact)
  const int hh_w = w >> 2, pq = w & 3;
  float mreg[2][4];
  #pragma unroll
  for (int pp = 0; pp < 2; ++pp) {
    int pair = pq * 2 + pp;
    #pragma unroll
    for (int r = 0; r < 4; ++r) {
      int row = fq * 4 + r;
      int Pg = mtile * 16 + pair * 2 + (row >> 3);
      mreg[pp][r] = mask[(size_t)Pg * 64 + (row & 7) * 8 + (fr & 7)];
    }
  }

  {  // zero-fill VT pad cols 128..143, both heads (512 thr cover 2x64x4 ushort4)
    int zh = t >> 8, d = (t >> 2) & 63, q = t & 3;
    ushort4 z; z.x = 0; z.y = 0; z.z = 0; z.w = 0;
    *(ushort4*)(smem + zh * 52224 + 32768 + d * 304 + 256 + q * 8) = z;
  }
  // spill acc -> per-head Qs/Ks/VT
  #pragma unroll
  for (int n = 0; n < 6; ++n) {
    int col = wn * 96 + n * 16 + fr;       // 0..383 (g/hh wave-uniform per n)
    int g = col >> 7, hh = (col >> 6) & 1, cc = col & 63;
    unsigned char* hb = smem + hh * 52224;
    #pragma unroll
    for (int m = 0; m < 4; ++m) {
      if (g == 2) {
        ushort4 p;
        p.x = f2bf(acc[m][n][0]); p.y = f2bf(acc[m][n][1]);
        p.z = f2bf(acc[m][n][2]); p.w = f2bf(acc[m][n][3]);
        *(ushort4*)(hb + 32768 + cc * 304 + (unsigned)(wm * 64 + m * 16 + fq * 4) * 2) = p;
      } else {
        unsigned char* T = hb + g * 16384;
        #pragma unroll
        for (int r = 0; r < 4; ++r) {
          int row = wm * 64 + m * 16 + fq * 4 + r;
          unsigned byte = (unsigned)row * 128 + (((unsigned)cc * 2) ^ (((unsigned)(row & 7)) << 4));
          *(unsigned short*)(T + byte) = f2bf(acc[m][n][r]);
        }
      }
    }
  }
  __syncthreads();

  // attention: wave w -> head hh_w, pairs pq*2+{0,1}
  unsigned char* hb = smem + hh_w * 52224;
  unsigned short* Qs = (unsigned short*)hb;
  unsigned short* Ks = (unsigned short*)(hb + 16384);
  unsigned char*  VTb = hb + 32768;

  #pragma unroll
  for (int pp = 0; pp < 2; ++pp) {
    const int pair = pq * 2 + pp;                 // pair within head, 0..7
    unsigned short* Pl = (unsigned short*)(smem + 104448) + (hh_w * 8 + pair) * 640;
    const unsigned rbyte = (unsigned)(pair * 16 + fr) * 128;
    const unsigned xrp = ((unsigned)(fr & 7)) << 4;
    // dots: S = Q . K^T (16x16; cross-pixel entries masked below)
    f32x4 s = {0.f, 0.f, 0.f, 0.f};
    #pragma unroll
    for (int kk = 0; kk < 2; ++kk) {
      const unsigned ko = ((unsigned)(kk * 64 + fq * 16)) ^ xrp;
      bf16x8 qf = *(const bf16x8*)((unsigned char*)Qs + rbyte + ko);
      bf16x8 kf = *(const bf16x8*)((unsigned char*)Ks + rbyte + ko);
      s = __builtin_amdgcn_mfma_f32_16x16x32_bf16(qf, kf, s, 0, 0, 0);
    }
    float p4[4];
    #pragma unroll
    for (int r = 0; r < 4; ++r) {
      int row = fq * 4 + r;
      bool valid = (row >> 3) == (fr >> 3);
      p4[r] = valid ? s[r] * SCALE_ * mreg[pp][r] : -3.0e38f;
    }
    #pragma unroll
    for (int r = 0; r < 4; ++r) {
      float v = p4[r];
      float mx = v;
      mx = fmaxf(mx, __shfl_xor(mx, 1));
      mx = fmaxf(mx, __shfl_xor(mx, 2));
      mx = fmaxf(mx, __shfl_xor(mx, 4));
      float e = __expf(v - mx);
      float sm = e;
      sm += __shfl_xor(sm, 1);
      sm += __shfl_xor(sm, 2);
      sm += __shfl_xor(sm, 4);
      p4[r] = e / sm;
    }
    #pragma unroll
    for (int r = 0; r < 4; ++r) {
      int row = fq * 4 + r;
      bool valid = (row >> 3) == (fr >> 3);
      Pl[row * 40 + fr] = valid ? f2bf(p4[r]) : (unsigned short)0;
      Pl[row * 40 + 16 + fr] = 0;
    }
    // PV: D[d][qi] = VT[d][j] . P[qi][j]  (K=32; j 16..31 zeros)
    #pragma unroll
    for (int dblk = 0; dblk < 4; ++dblk) {
      bf16x8 af = *(const bf16x8*)(VTb +
                    (unsigned)(dblk * 16 + fr) * 304 + (unsigned)(pair * 32 + fq * 16));
      bf16x8 bf = *(const bf16x8*)((unsigned char*)Pl +
                    (unsigned)fr * 80 + (unsigned)fq * 16);
      f32x4 o = {0.f, 0.f, 0.f, 0.f};
      o = __builtin_amdgcn_mfma_f32_16x16x32_bf16(af, bf, o, 0, 0, 0);
      ushort4 pk;
      pk.x = f2bf(o[0]); pk.y = f2bf(o[1]); pk.z = f2bf(o[2]); pk.w = f2bf(o[3]);
      *(ushort4*)(attn_out + (size_t)(r0 + pair * 16 + fr) * 512 +
                  (head0 + hh_w) * 64 + dblk * 16 + fq * 4) = pk;
    }
  }
}

// ---------------- K2: out = attn @ woutT^T + bias (f32 out) ----------------
// dbuf + global_load_lds + XOR-swizzle. 128x128 tile. (proven round-2 version)
__global__ __launch_bounds__(256, 2)
void outproj_kernel(const unsigned short* __restrict__ attn,
                    const unsigned short* __restrict__ woutT,
                    const float* __restrict__ bias,
                    float* __restrict__ out) {
  __shared__ __align__(16) unsigned char smem[65536];  // 2 x (A 16KB + B 16KB)
  const int t = threadIdx.x;
  const int lane = t & 63, wave = t >> 6;
  const int wm = wave >> 1, wn = wave & 1;
  const int fr = lane & 15, fq = lane >> 4;
  const int l8 = lane >> 3;
  const int cswz = ((lane & 7) ^ l8) * 8;

  const int per = gridDim.x >> 3;
  const int lin = (blockIdx.x & 7) * per + (blockIdx.x >> 3);
  const int mtile = lin >> 2, nt = lin & 3;
  const int r0 = mtile * 128, n0 = nt * 128;

  f32x4 acc[4][4];
  const f32x4 z4 = {0.f, 0.f, 0.f, 0.f};
  #pragma unroll
  for (int m = 0; m < 4; ++m)
    #pragma unroll
    for (int n = 0; n < 4; ++n) acc[m][n] = z4;

  auto STAGE = [&](int buf, int kt2) {
    unsigned char* base = smem + buf * 32768;
    const int k0 = kt2 * 64;
    const unsigned short* gA = attn  + (size_t)(r0 + l8) * 512 + k0 + cswz;
    const unsigned short* gB = woutT + (size_t)(n0 + l8) * 512 + k0 + cswz;
    #pragma unroll
    for (int i = 0; i < 4; ++i) {
      int c = wave * 4 + i;
      GLL16(gA + (size_t)c * 8 * 512, base + c * 1024);
      GLL16(gB + (size_t)c * 8 * 512, base + 16384 + c * 1024);
    }
  };

  STAGE(0, 0);
  VMCNT(0);
  __syncthreads();
  int cur = 0;

  for (int kt = 0; kt < 8; ++kt) {
    if (kt < 7) STAGE(cur ^ 1, kt + 1);
    unsigned char* Ab = smem + cur * 32768;
    unsigned char* Bb = Ab + 16384;
    const unsigned xr = ((unsigned)(fr & 7)) << 4;
    #pragma unroll
    for (int kk = 0; kk < 2; ++kk) {
      const unsigned ko = ((unsigned)(kk * 64 + fq * 16)) ^ xr;
      bf16x8 a[4], b[4];
      #pragma unroll
      for (int m = 0; m < 4; ++m)
        a[m] = *(const bf16x8*)(Ab + (unsigned)(wm * 64 + m * 16 + fr) * 128 + ko);
      #pragma unroll
      for (int n = 0; n < 4; ++n)
        b[n] = *(const bf16x8*)(Bb + (unsigned)(wn * 64 + n * 16 + fr) * 128 + ko);
      #pragma unroll
      for (int m = 0; m < 4; ++m)
        #pragma unroll
        for (int n = 0; n < 4; ++n)
          acc[m][n] = __builtin_amdgcn_mfma_f32_16x16x32_bf16(a[m], b[n], acc[m][n], 0, 0, 0);
    }
    VMCNT(0);
    __syncthreads();
    cur ^= 1;
  }
  #pragma unroll
  for (int n = 0; n < 4; ++n) {
    int col = n0 + wn * 64 + n * 16 + fr;
    float bv = bias[col];
    #pragma unroll
    for (int m = 0; m < 4; ++m) {
      #pragma unroll
      for (int j = 0; j < 4; ++j) {
        int row = r0 + wm * 64 + m * 16 + fq * 4 + j;
        out[(size_t)row * 512 + col] = acc[m][n][j] + bv;
      }
    }
  }
}

extern "C" void kernel_launch(void* const* d_in, const int* in_sizes, int n_in,
                              void* d_out, int out_size, void* d_ws, size_t ws_size,
                              hipStream_t stream) {
  const float* x    = (const float*)d_in[0];  // [65536][512]
  const float* mask = (const float*)d_in[1];  // [8192][8][8]
  const float* wqkv = (const float*)d_in[2];  // [512][1536]
  const float* wout = (const float*)d_in[3];  // [512][512]
  const float* bias = (const float*)d_in[4];  // [512]
  float* out = (float*)d_out;

  // ws: attn bf16 64MB | wqkvT 1.5MB | woutT 0.5MB | xb bf16 64MB (133.2MB, proven)
  unsigned char* ws = (unsigned char*)d_ws;
  unsigned short* attn  = (unsigned short*)ws;
  unsigned short* wqkvT = (unsigned short*)(ws + 67108864);
  unsigned short* woutT = (unsigned short*)(ws + 67108864 + 1572864);
  unsigned short* xb    = (unsigned short*)(ws + 67108864 + 1572864 + 524288);

  prep_kernel<<<20480, 256, 0, stream>>>(x, wqkv, wout, xb, wqkvT, woutT);
  qkv_attn_kernel<<<2048, 512, 0, stream>>>(xb, mask, wqkvT, attn);
  outproj_kernel<<<2048, 256, 0, stream>>>(attn, woutT, bias, out);
}